// Round 12
// baseline (409.241 us; speedup 1.0000x reference)
//
#include <hip/hip_runtime.h>

#define IN_DIM 128
#define SLW 128        // dst-slice width for the bucket sort (power of 2)
#define SLSH 7         // log2(SLW)
#define CAPS 6144      // per-slice pair capacity
#define EPA 4096       // edges per phase-A block
#define MAXSL 512      // static LDS sizing for phase A (>= nsl)

__device__ __forceinline__ float lrelu(float x) { return x > 0.f ? x : 0.2f * x; }

// order-preserving float->uint for atomicMax (0x00000000 == -inf sentinel)
__device__ __forceinline__ unsigned enc_f(float x) {
    unsigned b = __float_as_uint(x);
    return (b & 0x80000000u) ? ~b : (b | 0x80000000u);
}
__device__ __forceinline__ float dec_f(unsigned e) {
    unsigned b = (e & 0x80000000u) ? (e & 0x7fffffffu) : ~e;
    return __uint_as_float(b);
}

// ---- register-blocked node GEMM (HC=64, H=4) + fused logit epilogue +
//      global per-head als-max (upper bound for softmax shift) ----
template<int F>
__global__ __launch_bounds__(256) void gemm64_al_kernel(const float* __restrict__ in,
                                                        const float* __restrict__ W,
                                                        const float* __restrict__ a_s,
                                                        const float* __restrict__ a_d,
                                                        float* __restrict__ h,
                                                        float* __restrict__ als,
                                                        float* __restrict__ ald,
                                                        unsigned* __restrict__ gmax, int n) {
    constexpr int XS = F + 4;
    __shared__ float wl[F * 64];              // [k][col]
    __shared__ float xl[64 * XS];             // [node][k]
    __shared__ unsigned lmax[4];
    const int t = threadIdx.x;
    const int node0 = blockIdx.x * 64;
    if (t < 4) lmax[t] = 0u;
    for (int idx = t * 4; idx < F * 64; idx += 1024)
        *(float4*)&wl[idx] = *(const float4*)(W + idx);
    for (int idx = t * 4; idx < 64 * F; idx += 1024) {
        int node = idx / F, k = idx - node * F;
        float4 v = make_float4(0.f, 0.f, 0.f, 0.f);
        if (node0 + node < n) v = *(const float4*)(in + (size_t)(node0 + node) * F + k);
        *(float4*)&xl[node * XS + k] = v;
    }
    __syncthreads();

    const int tn = t >> 4;
    const int tc = t & 15;
    float4 acc[4] = {{0,0,0,0},{0,0,0,0},{0,0,0,0},{0,0,0,0}};

    for (int k0 = 0; k0 < F; k0 += 4) {
        float4 xa[4];
#pragma unroll
        for (int i = 0; i < 4; ++i) xa[i] = *(const float4*)&xl[(tn * 4 + i) * XS + k0];
#pragma unroll
        for (int kk = 0; kk < 4; ++kk) {
            float4 wv = *(const float4*)&wl[(k0 + kk) * 64 + tc * 4];
#pragma unroll
            for (int i = 0; i < 4; ++i) {
                float xv = (kk == 0) ? xa[i].x : (kk == 1) ? xa[i].y : (kk == 2) ? xa[i].z : xa[i].w;
                acc[i].x = fmaf(xv, wv.x, acc[i].x);
                acc[i].y = fmaf(xv, wv.y, acc[i].y);
                acc[i].z = fmaf(xv, wv.z, acc[i].z);
                acc[i].w = fmaf(xv, wv.w, acc[i].w);
            }
        }
    }

    const float4 asv = *(const float4*)(a_s + tc * 4);
    const float4 adv = *(const float4*)(a_d + tc * 4);
    float psmax = -1e30f;
#pragma unroll
    for (int i = 0; i < 4; ++i) {
        int node = node0 + tn * 4 + i;
        float ps = acc[i].x * asv.x + acc[i].y * asv.y + acc[i].z * asv.z + acc[i].w * asv.w;
        float pd = acc[i].x * adv.x + acc[i].y * adv.y + acc[i].z * adv.z + acc[i].w * adv.w;
        ps += __shfl_xor(ps, 1, 64); ps += __shfl_xor(ps, 2, 64);
        pd += __shfl_xor(pd, 1, 64); pd += __shfl_xor(pd, 2, 64);
        if (node < n) {
            psmax = fmaxf(psmax, ps);
            *(float4*)(h + (size_t)node * 64 + tc * 4) = acc[i];
            if ((t & 3) == 0) {
                int hd = tc >> 2;
                als[node * 4 + hd] = ps;
                ald[node * 4 + hd] = pd;
            }
        }
    }
    psmax = fmaxf(psmax, __shfl_xor(psmax, 16, 64));
    psmax = fmaxf(psmax, __shfl_xor(psmax, 32, 64));
    if ((t & 51) == 0) atomicMax(&lmax[(t >> 2) & 3], enc_f(psmax));
    __syncthreads();
    if (t < 4) atomicMax(gmax + t, lmax[t]);
}

// ---- legacy small GEMM (layer 3: HC=16, H=1) + fused logits + global als-max ----
template<int F, int HC, int H>
__global__ __launch_bounds__(256) void gemm_al_kernel(const float* __restrict__ in,
                                                      const float* __restrict__ W,
                                                      const float* __restrict__ a_s,
                                                      const float* __restrict__ a_d,
                                                      float* __restrict__ h,
                                                      float* __restrict__ als,
                                                      float* __restrict__ ald,
                                                      unsigned* __restrict__ gmax, int n) {
    constexpr int NPB = 256 / HC;
    __shared__ float wl[F * HC];
    __shared__ float xl[NPB * F];
    __shared__ unsigned lmax1;
    const int t = threadIdx.x;
    if (t == 0) lmax1 = 0u;
    for (int i = t; i < F * HC; i += 256) wl[i] = W[i];
    const int node0 = blockIdx.x * NPB;
    for (int i = t; i < NPB * F; i += 256) {
        int node = node0 + i / F;
        xl[i] = (node < n) ? in[node * F + (i % F)] : 0.f;
    }
    __syncthreads();
    const int nl = t / HC, col = t % HC;
    const int node = node0 + nl;
    float acc = 0.f;
#pragma unroll
    for (int k = 0; k < F; ++k) acc += xl[nl * F + k] * wl[k * HC + col];
    float ps = acc * a_s[col];
    float pd = acc * a_d[col];
#pragma unroll
    for (int msk = 1; msk < 16; msk <<= 1) {
        ps += __shfl_xor(ps, msk, 64);
        pd += __shfl_xor(pd, msk, 64);
    }
    if (node < n) {
        h[node * HC + col] = acc;
        if ((col & 15) == 0) {
            int head = col >> 4;
            als[node * H + head] = ps;
            ald[node * H + head] = pd;
        }
    }
    if (H == 1) {
        float psm = (node < n) ? ps : -1e30f;
        psm = fmaxf(psm, __shfl_xor(psm, 16, 64));
        psm = fmaxf(psm, __shfl_xor(psm, 32, 64));
        if ((t & 63) == 0) atomicMax(&lmax1, enc_f(psm));
        __syncthreads();
        if (t == 0) atomicMax(gmax, lmax1);
    }
}

// ---- CSR build phase A: partition edges into dst-slices (compact runs) ----
__global__ __launch_bounds__(256) void partition_kernel(const int* __restrict__ ei,
                                                        int* __restrict__ scur,
                                                        int2* __restrict__ pairs,
                                                        int ne, int n, int nsl) {
    __shared__ int lcnt[MAXSL], lbase[MAXSL], lcur[MAXSL];
    const int t = threadIdx.x;
    for (int i = t; i < MAXSL; i += 256) lcnt[i] = 0;
    __syncthreads();
    const int base = blockIdx.x * EPA;
    const int end = min(ne + n, base + EPA);
    for (int e = base + t; e < end; e += 256) {
        int d = (e < ne) ? ei[ne + e] : (e - ne);
        atomicAdd(&lcnt[d >> SLSH], 1);
    }
    __syncthreads();
    for (int s = t; s < nsl; s += 256) {
        lbase[s] = lcnt[s] ? atomicAdd(scur + s, lcnt[s]) : 0;
        lcur[s] = 0;
    }
    __syncthreads();
    for (int e = base + t; e < end; e += 256) {
        int s, d;
        if (e < ne) { s = ei[e]; d = ei[ne + e]; } else { s = d = e - ne; }
        int sl = d >> SLSH;
        int pos = lbase[sl] + atomicAdd(&lcur[sl], 1);
        if (pos < CAPS) pairs[(size_t)sl * CAPS + pos] = make_int2(s, d);
    }
}

// ---- exclusive scan of slice counts (nsl <= 512), one block ----
__global__ __launch_bounds__(512) void sscan_kernel(const int* __restrict__ scur,
                                                    int* __restrict__ sbase, int nsl) {
    __shared__ int sh[512];
    int t = threadIdx.x;
    int v = (t < nsl) ? scur[t] : 0;
    int orig = v;
    sh[t] = v;
    __syncthreads();
    for (int o = 1; o < 512; o <<= 1) {
        int other = (t >= o) ? sh[t - o] : 0;
        __syncthreads();
        v += other;
        sh[t] = v;
        __syncthreads();
    }
    if (t < nsl) sbase[t] = v - orig;  // exclusive
}

// ---- CSR build phase B: per-slice local counting sort, LDS-staged ----
__global__ __launch_bounds__(256) void buildcsr_kernel(const int2* __restrict__ pairs,
                                                       const int* __restrict__ scur,
                                                       const int* __restrict__ sbase,
                                                       int* __restrict__ csr,
                                                       int* __restrict__ off,
                                                       int n, int et, int nsl) {
    __shared__ int hist[SLW], hoff[SLW], hcur[SLW];
    __shared__ int lcsr[CAPS];
    __shared__ int hs[SLW];
    const int sl = blockIdx.x;
    const int lo = sl << SLSH;
    const int cnt = min(scur[sl], CAPS);
    const int gbase = sbase[sl];
    const int t = threadIdx.x;
    const int2* pp = pairs + (size_t)sl * CAPS;
    if (t < SLW) { hist[t] = 0; hcur[t] = 0; }
    __syncthreads();
    for (int i = t; i < cnt; i += 256) atomicAdd(&hist[pp[i].y - lo], 1);
    __syncthreads();
    if (t < SLW) hs[t] = hist[t];
    __syncthreads();
    for (int o = 1; o < SLW; o <<= 1) {
        int val = (t < SLW && t >= o) ? hs[t - o] : 0;
        __syncthreads();
        if (t < SLW) hs[t] += val;
        __syncthreads();
    }
    if (t < SLW) hoff[t] = hs[t] - hist[t];
    __syncthreads();
    if (t < SLW && lo + t < n) off[lo + t] = gbase + hoff[t];
    if (sl == nsl - 1 && t == 0) off[n] = et;
    for (int i = t; i < cnt; i += 256) {
        int2 p = pp[i];
        int dl = p.y - lo;
        int r = atomicAdd(&hcur[dl], 1);
        lcsr[hoff[dl] + r] = p.x;
    }
    __syncthreads();
    for (int i = t; i < cnt; i += 256) csr[gbase + i] = lcsr[i];
}

// ---- aggregation, H=4 C=16: single-pass, 32 edges/iter (8 gathers in flight) ----
__global__ __launch_bounds__(256) void agg64_kernel(const int* __restrict__ off,
                                                    const int* __restrict__ csr,
                                                    const float* __restrict__ als,
                                                    const float* __restrict__ ald,
                                                    const float* __restrict__ h,
                                                    const unsigned* __restrict__ gmax,
                                                    const float* __restrict__ bias,
                                                    const float* __restrict__ g,
                                                    const float* __restrict__ bb,
                                                    const float* __restrict__ mm,
                                                    const float* __restrict__ vv,
                                                    float* __restrict__ feat, int n) {
    int wave = (blockIdx.x * blockDim.x + threadIdx.x) >> 6;
    int lane = threadIdx.x & 63;
    if (wave >= n) return;
    const int start = off[wave], end = off[wave + 1], deg = end - start;

    const int ha = lane & 3;
    const int el = lane >> 2;
    const float alda = ald[(wave << 2) + ha];
    const float mh = lrelu(dec_f(gmax[ha]) + alda);  // upper bound (lrelu monotone)

    const int c4 = lane & 15;
    const int hd = c4 >> 2;
    const int eg = lane >> 4;
    float4 acc = {0.f, 0.f, 0.f, 0.f};
    float lsum = 0.f;
    for (int i = 0; i < deg; i += 32) {
        const int slot0 = i + el, slot1 = i + 16 + el;
        int s0 = csr[start + min(slot0, deg - 1)];
        int s1 = csr[start + min(slot1, deg - 1)];
        float w0 = __expf(lrelu(als[(s0 << 2) + ha] + alda) - mh);
        float w1 = __expf(lrelu(als[(s1 << 2) + ha] + alda) - mh);
        w0 = (slot0 < deg) ? w0 : 0.f;
        w1 = (slot1 < deg) ? w1 : 0.f;
        lsum += w0 + w1;
#pragma unroll
        for (int j0 = 0; j0 < 16; j0 += 4) {
            int srcl = ((j0 + eg) << 2) + hd;
            float wj0 = __shfl(w0, srcl, 64);
            int sj0 = __shfl(s0, srcl, 64);
            float wj1 = __shfl(w1, srcl, 64);
            int sj1 = __shfl(s1, srcl, 64);
            const float4 hv0 = *(const float4*)(h + (sj0 << 6) + (c4 << 2));
            const float4 hv1 = *(const float4*)(h + (sj1 << 6) + (c4 << 2));
            acc.x = fmaf(wj0, hv0.x, fmaf(wj1, hv1.x, acc.x));
            acc.y = fmaf(wj0, hv0.y, fmaf(wj1, hv1.y, acc.y));
            acc.z = fmaf(wj0, hv0.z, fmaf(wj1, hv1.z, acc.z));
            acc.w = fmaf(wj0, hv0.w, fmaf(wj1, hv1.w, acc.w));
        }
    }
#pragma unroll
    for (int msk = 4; msk < 64; msk <<= 1) lsum += __shfl_xor(lsum, msk, 64);
    float denom = __shfl(lsum, hd, 64);
#pragma unroll
    for (int msk = 16; msk < 64; msk <<= 1) {
        acc.x += __shfl_xor(acc.x, msk, 64);
        acc.y += __shfl_xor(acc.y, msk, 64);
        acc.z += __shfl_xor(acc.z, msk, 64);
        acc.w += __shfl_xor(acc.w, msk, 64);
    }
    if (lane < 16) {
        const int cb = c4 << 2;
        float inv = 1.f / (denom + 1e-16f);
        float4 bi = *(const float4*)(bias + cb);
        float4 gg = *(const float4*)(g + cb);
        float4 bbv = *(const float4*)(bb + cb);
        float4 mmv = *(const float4*)(mm + cb);
        float4 vvv = *(const float4*)(vv + cb);
        float4 o;
        o.x = fmaxf((acc.x * inv + bi.x - mmv.x) * rsqrtf(vvv.x + 1e-5f) * gg.x + bbv.x, 0.f);
        o.y = fmaxf((acc.y * inv + bi.y - mmv.y) * rsqrtf(vvv.y + 1e-5f) * gg.y + bbv.y, 0.f);
        o.z = fmaxf((acc.z * inv + bi.z - mmv.z) * rsqrtf(vvv.z + 1e-5f) * gg.z + bbv.z, 0.f);
        o.w = fmaxf((acc.w * inv + bi.w - mmv.w) * rsqrtf(vvv.w + 1e-5f) * gg.w + bbv.w, 0.f);
        *(float4*)(feat + ((size_t)wave << 6) + cb) = o;
    }
}

// ---- aggregation, H=1 C=16: single-pass (global-bound shift), exec-uniform ----
__global__ __launch_bounds__(256) void agg16_kernel(const int* __restrict__ off,
                                                    const int* __restrict__ csr,
                                                    const float* __restrict__ als,
                                                    const float* __restrict__ ald,
                                                    const float* __restrict__ h,
                                                    const unsigned* __restrict__ gmax,
                                                    const float* __restrict__ bias,
                                                    const float* __restrict__ g,
                                                    const float* __restrict__ bb,
                                                    const float* __restrict__ mm,
                                                    const float* __restrict__ vv,
                                                    float* __restrict__ feat, int n) {
    int wave = (blockIdx.x * blockDim.x + threadIdx.x) >> 6;
    int lane = threadIdx.x & 63;
    if (wave >= n) return;
    const int start = off[wave], end = off[wave + 1], deg = end - start;
    const float aldv = ald[wave];
    const float m = lrelu(dec_f(gmax[0]) + aldv);

    const int eg = lane >> 4, c = lane & 15;
    float acc = 0.f, lsum = 0.f;
    for (int i = 0; i < deg; i += 64) {
        int slot = i + lane;
        int s = csr[start + min(slot, deg - 1)];
        float w = __expf(lrelu(als[s] + aldv) - m);
        w = (slot < deg) ? w : 0.f;
        lsum += w;
#pragma unroll
        for (int j0 = 0; j0 < 64; j0 += 4) {
            int j = j0 + eg;
            float wj = __shfl(w, j, 64);
            int sj = __shfl(s, j, 64);
            acc = fmaf(wj, h[(sj << 4) + c], acc);
        }
    }
#pragma unroll
    for (int msk = 1; msk < 64; msk <<= 1) lsum += __shfl_xor(lsum, msk, 64);
#pragma unroll
    for (int msk = 16; msk < 64; msk <<= 1) acc += __shfl_xor(acc, msk, 64);
    if (lane < 16) {
        float val = acc / (lsum + 1e-16f) + bias[c];
        val = (val - mm[c]) * rsqrtf(vv[c] + 1e-5f) * g[c] + bb[c];
        feat[((size_t)wave << 4) + c] = fmaxf(val, 0.f);
    }
}

// ---------------- per-node MLP head: 16 -> relu(8) -> 1 ----------------
__global__ __launch_bounds__(256) void mlp_kernel(const float* __restrict__ feat,
                                                  const float* __restrict__ w1,
                                                  const float* __restrict__ b1,
                                                  const float* __restrict__ w2,
                                                  const float* __restrict__ b2,
                                                  float* __restrict__ out, int n) {
    int tid = blockIdx.x * blockDim.x + threadIdx.x;
    if (tid >= n) return;
    float f[16];
    const float4* fp = (const float4*)(feat + tid * 16);
#pragma unroll
    for (int i = 0; i < 4; ++i) {
        float4 v = fp[i];
        f[4 * i + 0] = v.x; f[4 * i + 1] = v.y; f[4 * i + 2] = v.z; f[4 * i + 3] = v.w;
    }
    float o = b2[0];
#pragma unroll
    for (int j = 0; j < 8; ++j) {
        float hv = b1[j];
#pragma unroll
        for (int i = 0; i < 16; ++i) hv += f[i] * w1[i * 8 + j];
        hv = fmaxf(hv, 0.f);
        o += hv * w2[j];
    }
    out[tid] = o;
}

extern "C" void kernel_launch(void* const* d_in, const int* in_sizes, int n_in,
                              void* d_out, int out_size, void* d_ws, size_t ws_size,
                              hipStream_t stream) {
    const float* x    = (const float*)d_in[0];
    const int*   ei   = (const int*)d_in[1];
    const float* W1   = (const float*)d_in[2];
    const float* As1  = (const float*)d_in[3];
    const float* Ad1  = (const float*)d_in[4];
    const float* b1   = (const float*)d_in[5];
    const float* bn1g = (const float*)d_in[6];
    const float* bn1b = (const float*)d_in[7];
    const float* bn1m = (const float*)d_in[8];
    const float* bn1v = (const float*)d_in[9];
    const float* W2   = (const float*)d_in[10];
    const float* As2  = (const float*)d_in[11];
    const float* Ad2  = (const float*)d_in[12];
    const float* b2   = (const float*)d_in[13];
    const float* bn2g = (const float*)d_in[14];
    const float* bn2b = (const float*)d_in[15];
    const float* bn2m = (const float*)d_in[16];
    const float* bn2v = (const float*)d_in[17];
    const float* W3   = (const float*)d_in[18];
    const float* As3  = (const float*)d_in[19];
    const float* Ad3  = (const float*)d_in[20];
    const float* b3   = (const float*)d_in[21];
    const float* bn3g = (const float*)d_in[22];
    const float* bn3b = (const float*)d_in[23];
    const float* bn3m = (const float*)d_in[24];
    const float* bn3v = (const float*)d_in[25];
    const float* fc1w = (const float*)d_in[26];
    const float* fc1b = (const float*)d_in[27];
    const float* fc2w = (const float*)d_in[28];
    const float* fc2b = (const float*)d_in[29];

    const int n  = in_sizes[0] / IN_DIM;  // 50000
    const int ne = in_sizes[1] / 2;       // 1600000
    const int et = ne + n;
    const int nsl = (n + SLW - 1) >> SLSH;  // 391

    float* h    = (float*)d_ws;
    float* feat = h + (size_t)n * 64;
    float* als  = feat + (size_t)n * 64;
    float* ald  = als + (size_t)n * 4;
    int2* pairs = (int2*)(ald + (size_t)n * 4);
    unsigned* gmax = (unsigned*)(pairs + (size_t)nsl * CAPS);  // gmax1[4] gmax2[4] gmax3[4]
    int* scur   = (int*)(gmax + 12);
    int* sbase  = scur + nsl;
    int* off    = sbase + nsl;
    int* csr    = off + (n + 1);

    auto cdiv = [](long a, long b) { return (int)((a + b - 1) / b); };

    // ---- zero gmax + scur in one memset; CSR build ----
    hipMemsetAsync(gmax, 0, (12 + (size_t)nsl) * sizeof(int), stream);
    partition_kernel<<<cdiv(et, EPA), 256, 0, stream>>>(ei, scur, pairs, ne, n, nsl);
    sscan_kernel<<<1, 512, 0, stream>>>(scur, sbase, nsl);
    buildcsr_kernel<<<nsl, 256, 0, stream>>>(pairs, scur, sbase, csr, off, n, et, nsl);

    // ---- Layer 1 ----
    gemm64_al_kernel<128><<<cdiv(n, 64), 256, 0, stream>>>(x, W1, As1, Ad1, h, als, ald, gmax, n);
    agg64_kernel<<<cdiv(n, 4), 256, 0, stream>>>(off, csr, als, ald, h, gmax,
        b1, bn1g, bn1b, bn1m, bn1v, feat, n);

    // ---- Layer 2 ----
    gemm64_al_kernel<64><<<cdiv(n, 64), 256, 0, stream>>>(feat, W2, As2, Ad2, h, als, ald, gmax + 4, n);
    agg64_kernel<<<cdiv(n, 4), 256, 0, stream>>>(off, csr, als, ald, h, gmax + 4,
        b2, bn2g, bn2b, bn2m, bn2v, feat, n);

    // ---- Layer 3 ----
    gemm_al_kernel<64, 16, 1><<<cdiv(n, 16), 256, 0, stream>>>(feat, W3, As3, Ad3, h, als, ald, gmax + 8, n);
    agg16_kernel<<<cdiv(n, 4), 256, 0, stream>>>(off, csr, als, ald, h, gmax + 8,
        b3, bn3g, bn3b, bn3m, bn3v, feat, n);

    // ---- MLP head ----
    mlp_kernel<<<cdiv(n, 256), 256, 0, stream>>>(feat, fc1w, fc1b, fc2w, fc2b,
                                                 (float*)d_out, n);
}

// Round 13
// 401.427 us; speedup vs baseline: 1.0195x; 1.0195x over previous
//
#include <hip/hip_runtime.h>

#define IN_DIM 128
#define SLW 128        // dst-slice width for the bucket sort (power of 2)
#define SLSH 7         // log2(SLW)
#define CAPS 6144      // per-slice pair capacity
#define EPA 4096       // edges per phase-A block
#define MAXSL 512      // static LDS sizing for phase A (>= nsl)

__device__ __forceinline__ float lrelu(float x) { return x > 0.f ? x : 0.2f * x; }

// order-preserving float->uint for atomicMax (0x00000000 == -inf sentinel)
__device__ __forceinline__ unsigned enc_f(float x) {
    unsigned b = __float_as_uint(x);
    return (b & 0x80000000u) ? ~b : (b | 0x80000000u);
}
__device__ __forceinline__ float dec_f(unsigned e) {
    unsigned b = (e & 0x80000000u) ? (e & 0x7fffffffu) : ~e;
    return __uint_as_float(b);
}

// ---- register-blocked node GEMM (HC=64, H=4) + fused logit epilogue +
//      global per-head als-max (upper bound for softmax shift) ----
template<int F>
__global__ __launch_bounds__(256) void gemm64_al_kernel(const float* __restrict__ in,
                                                        const float* __restrict__ W,
                                                        const float* __restrict__ a_s,
                                                        const float* __restrict__ a_d,
                                                        float* __restrict__ h,
                                                        float* __restrict__ als,
                                                        float* __restrict__ ald,
                                                        unsigned* __restrict__ gmax, int n) {
    constexpr int XS = F + 4;
    __shared__ float wl[F * 64];              // [k][col]
    __shared__ float xl[64 * XS];             // [node][k]
    __shared__ unsigned lmax[4];
    const int t = threadIdx.x;
    const int node0 = blockIdx.x * 64;
    if (t < 4) lmax[t] = 0u;
    for (int idx = t * 4; idx < F * 64; idx += 1024)
        *(float4*)&wl[idx] = *(const float4*)(W + idx);
    for (int idx = t * 4; idx < 64 * F; idx += 1024) {
        int node = idx / F, k = idx - node * F;
        float4 v = make_float4(0.f, 0.f, 0.f, 0.f);
        if (node0 + node < n) v = *(const float4*)(in + (size_t)(node0 + node) * F + k);
        *(float4*)&xl[node * XS + k] = v;
    }
    __syncthreads();

    const int tn = t >> 4;
    const int tc = t & 15;
    float4 acc[4] = {{0,0,0,0},{0,0,0,0},{0,0,0,0},{0,0,0,0}};

    for (int k0 = 0; k0 < F; k0 += 4) {
        float4 xa[4];
#pragma unroll
        for (int i = 0; i < 4; ++i) xa[i] = *(const float4*)&xl[(tn * 4 + i) * XS + k0];
#pragma unroll
        for (int kk = 0; kk < 4; ++kk) {
            float4 wv = *(const float4*)&wl[(k0 + kk) * 64 + tc * 4];
#pragma unroll
            for (int i = 0; i < 4; ++i) {
                float xv = (kk == 0) ? xa[i].x : (kk == 1) ? xa[i].y : (kk == 2) ? xa[i].z : xa[i].w;
                acc[i].x = fmaf(xv, wv.x, acc[i].x);
                acc[i].y = fmaf(xv, wv.y, acc[i].y);
                acc[i].z = fmaf(xv, wv.z, acc[i].z);
                acc[i].w = fmaf(xv, wv.w, acc[i].w);
            }
        }
    }

    const float4 asv = *(const float4*)(a_s + tc * 4);
    const float4 adv = *(const float4*)(a_d + tc * 4);
    float psmax = -1e30f;
#pragma unroll
    for (int i = 0; i < 4; ++i) {
        int node = node0 + tn * 4 + i;
        float ps = acc[i].x * asv.x + acc[i].y * asv.y + acc[i].z * asv.z + acc[i].w * asv.w;
        float pd = acc[i].x * adv.x + acc[i].y * adv.y + acc[i].z * adv.z + acc[i].w * adv.w;
        ps += __shfl_xor(ps, 1, 64); ps += __shfl_xor(ps, 2, 64);
        pd += __shfl_xor(pd, 1, 64); pd += __shfl_xor(pd, 2, 64);
        if (node < n) {
            psmax = fmaxf(psmax, ps);
            *(float4*)(h + (size_t)node * 64 + tc * 4) = acc[i];
            if ((t & 3) == 0) {
                int hd = tc >> 2;
                als[node * 4 + hd] = ps;
                ald[node * 4 + hd] = pd;
            }
        }
    }
    psmax = fmaxf(psmax, __shfl_xor(psmax, 16, 64));
    psmax = fmaxf(psmax, __shfl_xor(psmax, 32, 64));
    if ((t & 51) == 0) atomicMax(&lmax[(t >> 2) & 3], enc_f(psmax));
    __syncthreads();
    if (t < 4) atomicMax(gmax + t, lmax[t]);
}

// ---- legacy small GEMM (layer 3: HC=16, H=1) + fused logits + global als-max ----
template<int F, int HC, int H>
__global__ __launch_bounds__(256) void gemm_al_kernel(const float* __restrict__ in,
                                                      const float* __restrict__ W,
                                                      const float* __restrict__ a_s,
                                                      const float* __restrict__ a_d,
                                                      float* __restrict__ h,
                                                      float* __restrict__ als,
                                                      float* __restrict__ ald,
                                                      unsigned* __restrict__ gmax, int n) {
    constexpr int NPB = 256 / HC;
    __shared__ float wl[F * HC];
    __shared__ float xl[NPB * F];
    __shared__ unsigned lmax1;
    const int t = threadIdx.x;
    if (t == 0) lmax1 = 0u;
    for (int i = t; i < F * HC; i += 256) wl[i] = W[i];
    const int node0 = blockIdx.x * NPB;
    for (int i = t; i < NPB * F; i += 256) {
        int node = node0 + i / F;
        xl[i] = (node < n) ? in[node * F + (i % F)] : 0.f;
    }
    __syncthreads();
    const int nl = t / HC, col = t % HC;
    const int node = node0 + nl;
    float acc = 0.f;
#pragma unroll
    for (int k = 0; k < F; ++k) acc += xl[nl * F + k] * wl[k * HC + col];
    float ps = acc * a_s[col];
    float pd = acc * a_d[col];
#pragma unroll
    for (int msk = 1; msk < 16; msk <<= 1) {
        ps += __shfl_xor(ps, msk, 64);
        pd += __shfl_xor(pd, msk, 64);
    }
    if (node < n) {
        h[node * HC + col] = acc;
        if ((col & 15) == 0) {
            int head = col >> 4;
            als[node * H + head] = ps;
            ald[node * H + head] = pd;
        }
    }
    if (H == 1) {
        float psm = (node < n) ? ps : -1e30f;
        psm = fmaxf(psm, __shfl_xor(psm, 16, 64));
        psm = fmaxf(psm, __shfl_xor(psm, 32, 64));
        if ((t & 63) == 0) atomicMax(&lmax1, enc_f(psm));
        __syncthreads();
        if (t == 0) atomicMax(gmax, lmax1);
    }
}

// ---- CSR build phase A: partition edges into dst-slices (compact runs) ----
__global__ __launch_bounds__(256) void partition_kernel(const int* __restrict__ ei,
                                                        int* __restrict__ scur,
                                                        int2* __restrict__ pairs,
                                                        int ne, int n, int nsl) {
    __shared__ int lcnt[MAXSL], lbase[MAXSL], lcur[MAXSL];
    const int t = threadIdx.x;
    for (int i = t; i < MAXSL; i += 256) lcnt[i] = 0;
    __syncthreads();
    const int base = blockIdx.x * EPA;
    const int end = min(ne + n, base + EPA);
    for (int e = base + t; e < end; e += 256) {
        int d = (e < ne) ? ei[ne + e] : (e - ne);
        atomicAdd(&lcnt[d >> SLSH], 1);
    }
    __syncthreads();
    for (int s = t; s < nsl; s += 256) {
        lbase[s] = lcnt[s] ? atomicAdd(scur + s, lcnt[s]) : 0;
        lcur[s] = 0;
    }
    __syncthreads();
    for (int e = base + t; e < end; e += 256) {
        int s, d;
        if (e < ne) { s = ei[e]; d = ei[ne + e]; } else { s = d = e - ne; }
        int sl = d >> SLSH;
        int pos = lbase[sl] + atomicAdd(&lcur[sl], 1);
        if (pos < CAPS) pairs[(size_t)sl * CAPS + pos] = make_int2(s, d);
    }
}

// ---- CSR build phase B: per-slice local counting sort, LDS-staged.
//      Each block computes its own global base (inline prefix over scur). ----
__global__ __launch_bounds__(256) void buildcsr_kernel(const int2* __restrict__ pairs,
                                                       const int* __restrict__ scur,
                                                       int* __restrict__ csr,
                                                       int* __restrict__ off,
                                                       int n, int et, int nsl) {
    __shared__ int hist[SLW], hoff[SLW], hcur[SLW];
    __shared__ int lcsr[CAPS];
    __shared__ int hs[SLW];
    __shared__ int red[256];
    const int sl = blockIdx.x;
    const int lo = sl << SLSH;
    const int t = threadIdx.x;
    // inline exclusive prefix: gbase = sum_{s<sl} scur[s]
    int partial = 0;
    for (int i = t; i < sl; i += 256) partial += scur[i];
    red[t] = partial;
    __syncthreads();
    for (int o = 128; o > 0; o >>= 1) {
        if (t < o) red[t] += red[t + o];
        __syncthreads();
    }
    const int gbase = red[0];
    const int cnt = min(scur[sl], CAPS);
    const int2* pp = pairs + (size_t)sl * CAPS;
    if (t < SLW) { hist[t] = 0; hcur[t] = 0; }
    __syncthreads();
    for (int i = t; i < cnt; i += 256) atomicAdd(&hist[pp[i].y - lo], 1);
    __syncthreads();
    if (t < SLW) hs[t] = hist[t];
    __syncthreads();
    for (int o = 1; o < SLW; o <<= 1) {
        int val = (t < SLW && t >= o) ? hs[t - o] : 0;
        __syncthreads();
        if (t < SLW) hs[t] += val;
        __syncthreads();
    }
    if (t < SLW) hoff[t] = hs[t] - hist[t];
    __syncthreads();
    if (t < SLW && lo + t < n) off[lo + t] = gbase + hoff[t];
    if (sl == nsl - 1 && t == 0) off[n] = et;
    for (int i = t; i < cnt; i += 256) {
        int2 p = pp[i];
        int dl = p.y - lo;
        int r = atomicAdd(&hcur[dl], 1);
        lcsr[hoff[dl] + r] = p.x;
    }
    __syncthreads();
    for (int i = t; i < cnt; i += 256) csr[gbase + i] = lcsr[i];
}

// ---- aggregation, H=4 C=16: single-pass (global-bound softmax shift) ----
__global__ __launch_bounds__(256) void agg64_kernel(const int* __restrict__ off,
                                                    const int* __restrict__ csr,
                                                    const float* __restrict__ als,
                                                    const float* __restrict__ ald,
                                                    const float* __restrict__ h,
                                                    const unsigned* __restrict__ gmax,
                                                    const float* __restrict__ bias,
                                                    const float* __restrict__ g,
                                                    const float* __restrict__ bb,
                                                    const float* __restrict__ mm,
                                                    const float* __restrict__ vv,
                                                    float* __restrict__ feat, int n) {
    int wave = (blockIdx.x * blockDim.x + threadIdx.x) >> 6;
    int lane = threadIdx.x & 63;
    if (wave >= n) return;
    const int start = off[wave], end = off[wave + 1], deg = end - start;

    const int ha = lane & 3;
    const int el = lane >> 2;
    const float alda = ald[(wave << 2) + ha];
    const float mh = lrelu(dec_f(gmax[ha]) + alda);  // upper bound (lrelu monotone)

    const int c4 = lane & 15;
    const int hd = c4 >> 2;
    const int eg = lane >> 4;
    float4 acc = {0.f, 0.f, 0.f, 0.f};
    float lsum = 0.f;
    for (int i = 0; i < deg; i += 16) {
        int slot = i + el;
        int s = csr[start + min(slot, deg - 1)];
        float w = __expf(lrelu(als[(s << 2) + ha] + alda) - mh);
        w = (slot < deg) ? w : 0.f;
        lsum += w;
#pragma unroll
        for (int j0 = 0; j0 < 16; j0 += 4) {
            int srcl = ((j0 + eg) << 2) + hd;
            float wj = __shfl(w, srcl, 64);
            int sj = __shfl(s, srcl, 64);
            const float4 hv = *(const float4*)(h + (sj << 6) + (c4 << 2));
            acc.x = fmaf(wj, hv.x, acc.x);
            acc.y = fmaf(wj, hv.y, acc.y);
            acc.z = fmaf(wj, hv.z, acc.z);
            acc.w = fmaf(wj, hv.w, acc.w);
        }
    }
#pragma unroll
    for (int msk = 4; msk < 64; msk <<= 1) lsum += __shfl_xor(lsum, msk, 64);
    float denom = __shfl(lsum, hd, 64);
#pragma unroll
    for (int msk = 16; msk < 64; msk <<= 1) {
        acc.x += __shfl_xor(acc.x, msk, 64);
        acc.y += __shfl_xor(acc.y, msk, 64);
        acc.z += __shfl_xor(acc.z, msk, 64);
        acc.w += __shfl_xor(acc.w, msk, 64);
    }
    if (lane < 16) {
        const int cb = c4 << 2;
        float inv = 1.f / (denom + 1e-16f);
        float4 bi = *(const float4*)(bias + cb);
        float4 gg = *(const float4*)(g + cb);
        float4 bbv = *(const float4*)(bb + cb);
        float4 mmv = *(const float4*)(mm + cb);
        float4 vvv = *(const float4*)(vv + cb);
        float4 o;
        o.x = fmaxf((acc.x * inv + bi.x - mmv.x) * rsqrtf(vvv.x + 1e-5f) * gg.x + bbv.x, 0.f);
        o.y = fmaxf((acc.y * inv + bi.y - mmv.y) * rsqrtf(vvv.y + 1e-5f) * gg.y + bbv.y, 0.f);
        o.z = fmaxf((acc.z * inv + bi.z - mmv.z) * rsqrtf(vvv.z + 1e-5f) * gg.z + bbv.z, 0.f);
        o.w = fmaxf((acc.w * inv + bi.w - mmv.w) * rsqrtf(vvv.w + 1e-5f) * gg.w + bbv.w, 0.f);
        *(float4*)(feat + ((size_t)wave << 6) + cb) = o;
    }
}

// ---- aggregation, H=1 C=16, FUSED with BN/ReLU and the 16->8->1 MLP head.
//      Writes d_out directly; feat round-trip eliminated. ----
__global__ __launch_bounds__(256) void agg16_mlp_kernel(const int* __restrict__ off,
                                                        const int* __restrict__ csr,
                                                        const float* __restrict__ als,
                                                        const float* __restrict__ ald,
                                                        const float* __restrict__ h,
                                                        const unsigned* __restrict__ gmax,
                                                        const float* __restrict__ bias,
                                                        const float* __restrict__ g,
                                                        const float* __restrict__ bb,
                                                        const float* __restrict__ mm,
                                                        const float* __restrict__ vv,
                                                        const float* __restrict__ w1,
                                                        const float* __restrict__ b1,
                                                        const float* __restrict__ w2,
                                                        const float* __restrict__ b2,
                                                        float* __restrict__ out, int n) {
    int wave = (blockIdx.x * blockDim.x + threadIdx.x) >> 6;
    int lane = threadIdx.x & 63;
    if (wave >= n) return;
    const int start = off[wave], end = off[wave + 1], deg = end - start;
    const float aldv = ald[wave];
    const float m = lrelu(dec_f(gmax[0]) + aldv);

    const int eg = lane >> 4, c = lane & 15;
    float acc = 0.f, lsum = 0.f;
    for (int i = 0; i < deg; i += 64) {
        int slot = i + lane;
        int s = csr[start + min(slot, deg - 1)];
        float w = __expf(lrelu(als[s] + aldv) - m);
        w = (slot < deg) ? w : 0.f;
        lsum += w;
#pragma unroll
        for (int j0 = 0; j0 < 64; j0 += 4) {
            int j = j0 + eg;
            float wj = __shfl(w, j, 64);
            int sj = __shfl(s, j, 64);
            acc = fmaf(wj, h[(sj << 4) + c], acc);
        }
    }
    // after these xor-butterflies every lane holds the full sums
#pragma unroll
    for (int msk = 1; msk < 64; msk <<= 1) lsum += __shfl_xor(lsum, msk, 64);
#pragma unroll
    for (int msk = 16; msk < 64; msk <<= 1) acc += __shfl_xor(acc, msk, 64);

    // feat value for channel c (replicated across the 4 eg groups)
    float val = acc / (lsum + 1e-16f) + bias[c];
    val = (val - mm[c]) * rsqrtf(vv[c] + 1e-5f) * g[c] + bb[c];
    val = fmaxf(val, 0.f);

    // MLP 16 -> relu(8) -> 1: lane (c, eg) handles hidden j0=2eg, j1=2eg+1
    const int j0 = eg * 2, j1 = j0 + 1;
    float p0 = val * w1[c * 8 + j0];
    float p1 = val * w1[c * 8 + j1];
#pragma unroll
    for (int msk = 1; msk < 16; msk <<= 1) {
        p0 += __shfl_xor(p0, msk, 64);
        p1 += __shfl_xor(p1, msk, 64);
    }
    float hv0 = fmaxf(p0 + b1[j0], 0.f);
    float hv1 = fmaxf(p1 + b1[j1], 0.f);
    float o = hv0 * w2[j0] + hv1 * w2[j1];
#pragma unroll
    for (int msk = 16; msk < 64; msk <<= 1) o += __shfl_xor(o, msk, 64);
    if (lane == 0) out[wave] = o + b2[0];
}

extern "C" void kernel_launch(void* const* d_in, const int* in_sizes, int n_in,
                              void* d_out, int out_size, void* d_ws, size_t ws_size,
                              hipStream_t stream) {
    const float* x    = (const float*)d_in[0];
    const int*   ei   = (const int*)d_in[1];
    const float* W1   = (const float*)d_in[2];
    const float* As1  = (const float*)d_in[3];
    const float* Ad1  = (const float*)d_in[4];
    const float* b1   = (const float*)d_in[5];
    const float* bn1g = (const float*)d_in[6];
    const float* bn1b = (const float*)d_in[7];
    const float* bn1m = (const float*)d_in[8];
    const float* bn1v = (const float*)d_in[9];
    const float* W2   = (const float*)d_in[10];
    const float* As2  = (const float*)d_in[11];
    const float* Ad2  = (const float*)d_in[12];
    const float* b2   = (const float*)d_in[13];
    const float* bn2g = (const float*)d_in[14];
    const float* bn2b = (const float*)d_in[15];
    const float* bn2m = (const float*)d_in[16];
    const float* bn2v = (const float*)d_in[17];
    const float* W3   = (const float*)d_in[18];
    const float* As3  = (const float*)d_in[19];
    const float* Ad3  = (const float*)d_in[20];
    const float* b3   = (const float*)d_in[21];
    const float* bn3g = (const float*)d_in[22];
    const float* bn3b = (const float*)d_in[23];
    const float* bn3m = (const float*)d_in[24];
    const float* bn3v = (const float*)d_in[25];
    const float* fc1w = (const float*)d_in[26];
    const float* fc1b = (const float*)d_in[27];
    const float* fc2w = (const float*)d_in[28];
    const float* fc2b = (const float*)d_in[29];

    const int n  = in_sizes[0] / IN_DIM;  // 50000
    const int ne = in_sizes[1] / 2;       // 1600000
    const int et = ne + n;
    const int nsl = (n + SLW - 1) >> SLSH;  // 391

    float* h    = (float*)d_ws;
    float* feat = h + (size_t)n * 64;
    float* als  = feat + (size_t)n * 64;
    float* ald  = als + (size_t)n * 4;
    int2* pairs = (int2*)(ald + (size_t)n * 4);
    unsigned* gmax = (unsigned*)(pairs + (size_t)nsl * CAPS);  // gmax1[4] gmax2[4] gmax3[4]
    int* scur   = (int*)(gmax + 12);
    int* off    = scur + nsl;
    int* csr    = off + (n + 1);

    auto cdiv = [](long a, long b) { return (int)((a + b - 1) / b); };

    // ---- zero gmax + scur in one memset; CSR build (2 kernels) ----
    hipMemsetAsync(gmax, 0, (12 + (size_t)nsl) * sizeof(int), stream);
    partition_kernel<<<cdiv(et, EPA), 256, 0, stream>>>(ei, scur, pairs, ne, n, nsl);
    buildcsr_kernel<<<nsl, 256, 0, stream>>>(pairs, scur, csr, off, n, et, nsl);

    // ---- Layer 1 ----
    gemm64_al_kernel<128><<<cdiv(n, 64), 256, 0, stream>>>(x, W1, As1, Ad1, h, als, ald, gmax, n);
    agg64_kernel<<<cdiv(n, 4), 256, 0, stream>>>(off, csr, als, ald, h, gmax,
        b1, bn1g, bn1b, bn1m, bn1v, feat, n);

    // ---- Layer 2 ----
    gemm64_al_kernel<64><<<cdiv(n, 64), 256, 0, stream>>>(feat, W2, As2, Ad2, h, als, ald, gmax + 4, n);
    agg64_kernel<<<cdiv(n, 4), 256, 0, stream>>>(off, csr, als, ald, h, gmax + 4,
        b2, bn2g, bn2b, bn2m, bn2v, feat, n);

    // ---- Layer 3 (agg + BN + MLP fused, writes d_out) ----
    gemm_al_kernel<64, 16, 1><<<cdiv(n, 16), 256, 0, stream>>>(feat, W3, As3, Ad3, h, als, ald, gmax + 8, n);
    agg16_mlp_kernel<<<cdiv(n, 4), 256, 0, stream>>>(off, csr, als, ald, h, gmax + 8,
        b3, bn3g, bn3b, bn3m, bn3v, fc1w, fc1b, fc2w, fc2b, (float*)d_out, n);
}

// Round 14
// 392.254 us; speedup vs baseline: 1.0433x; 1.0234x over previous
//
#include <hip/hip_runtime.h>

#define IN_DIM 128
#define SLW 128        // dst-slice width for the bucket sort (power of 2)
#define SLSH 7         // log2(SLW)
#define CAPS 6144      // per-slice pair capacity
#define EPA 4096       // edges per phase-A block
#define MAXSL 512      // static LDS sizing for phase A (>= nsl)

__device__ __forceinline__ float lrelu(float x) { return x > 0.f ? x : 0.2f * x; }

// order-preserving float->uint for atomicMax (0x00000000 == -inf sentinel)
__device__ __forceinline__ unsigned enc_f(float x) {
    unsigned b = __float_as_uint(x);
    return (b & 0x80000000u) ? ~b : (b | 0x80000000u);
}
__device__ __forceinline__ float dec_f(unsigned e) {
    unsigned b = (e & 0x80000000u) ? (e & 0x7fffffffu) : ~e;
    return __uint_as_float(b);
}

// ---- MERGED: edge partition (blocks [0, pblocks)) + register-blocked L1 GEMM
//      (blocks [pblocks, ...)). The two are independent; merging lets them
//      co-schedule instead of serializing on the stream. ----
__global__ __launch_bounds__(256) void part_gemm1_kernel(const int* __restrict__ ei,
                                                         int* __restrict__ scur,
                                                         int2* __restrict__ pairs,
                                                         int ne, int n, int nsl, int pblocks,
                                                         const float* __restrict__ in,
                                                         const float* __restrict__ W,
                                                         const float* __restrict__ a_s,
                                                         const float* __restrict__ a_d,
                                                         float* __restrict__ h,
                                                         float* __restrict__ als,
                                                         float* __restrict__ ald,
                                                         unsigned* __restrict__ gmax) {
    constexpr int F = 128;
    constexpr int XS = F + 4;
    __shared__ int lcnt[MAXSL], lbase[MAXSL], lcur[MAXSL];
    __shared__ float wl[F * 64];
    __shared__ float xl[64 * XS];
    __shared__ unsigned lmax[4];
    const int t = threadIdx.x;

    if (blockIdx.x < pblocks) {
        // ---------------- partition path ----------------
        for (int i = t; i < MAXSL; i += 256) lcnt[i] = 0;
        __syncthreads();
        const int base = blockIdx.x * EPA;
        const int end = min(ne + n, base + EPA);
        for (int e = base + t; e < end; e += 256) {
            int d = (e < ne) ? ei[ne + e] : (e - ne);
            atomicAdd(&lcnt[d >> SLSH], 1);
        }
        __syncthreads();
        for (int s = t; s < nsl; s += 256) {
            lbase[s] = lcnt[s] ? atomicAdd(scur + s, lcnt[s]) : 0;
            lcur[s] = 0;
        }
        __syncthreads();
        for (int e = base + t; e < end; e += 256) {
            int s, d;
            if (e < ne) { s = ei[e]; d = ei[ne + e]; } else { s = d = e - ne; }
            int sl = d >> SLSH;
            int pos = lbase[sl] + atomicAdd(&lcur[sl], 1);
            if (pos < CAPS) pairs[(size_t)sl * CAPS + pos] = make_int2(s, d);
        }
        return;
    }

    // ---------------- gemm64 path (layer 1, F=128) ----------------
    const int node0 = (blockIdx.x - pblocks) * 64;
    if (t < 4) lmax[t] = 0u;
    for (int idx = t * 4; idx < F * 64; idx += 1024)
        *(float4*)&wl[idx] = *(const float4*)(W + idx);
    for (int idx = t * 4; idx < 64 * F; idx += 1024) {
        int node = idx / F, k = idx - node * F;
        float4 v = make_float4(0.f, 0.f, 0.f, 0.f);
        if (node0 + node < n) v = *(const float4*)(in + (size_t)(node0 + node) * F + k);
        *(float4*)&xl[node * XS + k] = v;
    }
    __syncthreads();

    const int tn = t >> 4;
    const int tc = t & 15;
    float4 acc[4] = {{0,0,0,0},{0,0,0,0},{0,0,0,0},{0,0,0,0}};
    for (int k0 = 0; k0 < F; k0 += 4) {
        float4 xa[4];
#pragma unroll
        for (int i = 0; i < 4; ++i) xa[i] = *(const float4*)&xl[(tn * 4 + i) * XS + k0];
#pragma unroll
        for (int kk = 0; kk < 4; ++kk) {
            float4 wv = *(const float4*)&wl[(k0 + kk) * 64 + tc * 4];
#pragma unroll
            for (int i = 0; i < 4; ++i) {
                float xv = (kk == 0) ? xa[i].x : (kk == 1) ? xa[i].y : (kk == 2) ? xa[i].z : xa[i].w;
                acc[i].x = fmaf(xv, wv.x, acc[i].x);
                acc[i].y = fmaf(xv, wv.y, acc[i].y);
                acc[i].z = fmaf(xv, wv.z, acc[i].z);
                acc[i].w = fmaf(xv, wv.w, acc[i].w);
            }
        }
    }
    const float4 asv = *(const float4*)(a_s + tc * 4);
    const float4 adv = *(const float4*)(a_d + tc * 4);
    float psmax = -1e30f;
#pragma unroll
    for (int i = 0; i < 4; ++i) {
        int node = node0 + tn * 4 + i;
        float ps = acc[i].x * asv.x + acc[i].y * asv.y + acc[i].z * asv.z + acc[i].w * asv.w;
        float pd = acc[i].x * adv.x + acc[i].y * adv.y + acc[i].z * adv.z + acc[i].w * adv.w;
        ps += __shfl_xor(ps, 1, 64); ps += __shfl_xor(ps, 2, 64);
        pd += __shfl_xor(pd, 1, 64); pd += __shfl_xor(pd, 2, 64);
        if (node < n) {
            psmax = fmaxf(psmax, ps);
            *(float4*)(h + (size_t)node * 64 + tc * 4) = acc[i];
            if ((t & 3) == 0) {
                int hd = tc >> 2;
                als[node * 4 + hd] = ps;
                ald[node * 4 + hd] = pd;
            }
        }
    }
    psmax = fmaxf(psmax, __shfl_xor(psmax, 16, 64));
    psmax = fmaxf(psmax, __shfl_xor(psmax, 32, 64));
    if ((t & 51) == 0) atomicMax(&lmax[(t >> 2) & 3], enc_f(psmax));
    __syncthreads();
    if (t < 4) atomicMax(gmax + t, lmax[t]);
}

// ---- register-blocked node GEMM (HC=64, H=4), standalone (layer 2) ----
template<int F>
__global__ __launch_bounds__(256) void gemm64_al_kernel(const float* __restrict__ in,
                                                        const float* __restrict__ W,
                                                        const float* __restrict__ a_s,
                                                        const float* __restrict__ a_d,
                                                        float* __restrict__ h,
                                                        float* __restrict__ als,
                                                        float* __restrict__ ald,
                                                        unsigned* __restrict__ gmax, int n) {
    constexpr int XS = F + 4;
    __shared__ float wl[F * 64];
    __shared__ float xl[64 * XS];
    __shared__ unsigned lmax[4];
    const int t = threadIdx.x;
    const int node0 = blockIdx.x * 64;
    if (t < 4) lmax[t] = 0u;
    for (int idx = t * 4; idx < F * 64; idx += 1024)
        *(float4*)&wl[idx] = *(const float4*)(W + idx);
    for (int idx = t * 4; idx < 64 * F; idx += 1024) {
        int node = idx / F, k = idx - node * F;
        float4 v = make_float4(0.f, 0.f, 0.f, 0.f);
        if (node0 + node < n) v = *(const float4*)(in + (size_t)(node0 + node) * F + k);
        *(float4*)&xl[node * XS + k] = v;
    }
    __syncthreads();

    const int tn = t >> 4;
    const int tc = t & 15;
    float4 acc[4] = {{0,0,0,0},{0,0,0,0},{0,0,0,0},{0,0,0,0}};
    for (int k0 = 0; k0 < F; k0 += 4) {
        float4 xa[4];
#pragma unroll
        for (int i = 0; i < 4; ++i) xa[i] = *(const float4*)&xl[(tn * 4 + i) * XS + k0];
#pragma unroll
        for (int kk = 0; kk < 4; ++kk) {
            float4 wv = *(const float4*)&wl[(k0 + kk) * 64 + tc * 4];
#pragma unroll
            for (int i = 0; i < 4; ++i) {
                float xv = (kk == 0) ? xa[i].x : (kk == 1) ? xa[i].y : (kk == 2) ? xa[i].z : xa[i].w;
                acc[i].x = fmaf(xv, wv.x, acc[i].x);
                acc[i].y = fmaf(xv, wv.y, acc[i].y);
                acc[i].z = fmaf(xv, wv.z, acc[i].z);
                acc[i].w = fmaf(xv, wv.w, acc[i].w);
            }
        }
    }
    const float4 asv = *(const float4*)(a_s + tc * 4);
    const float4 adv = *(const float4*)(a_d + tc * 4);
    float psmax = -1e30f;
#pragma unroll
    for (int i = 0; i < 4; ++i) {
        int node = node0 + tn * 4 + i;
        float ps = acc[i].x * asv.x + acc[i].y * asv.y + acc[i].z * asv.z + acc[i].w * asv.w;
        float pd = acc[i].x * adv.x + acc[i].y * adv.y + acc[i].z * adv.z + acc[i].w * adv.w;
        ps += __shfl_xor(ps, 1, 64); ps += __shfl_xor(ps, 2, 64);
        pd += __shfl_xor(pd, 1, 64); pd += __shfl_xor(pd, 2, 64);
        if (node < n) {
            psmax = fmaxf(psmax, ps);
            *(float4*)(h + (size_t)node * 64 + tc * 4) = acc[i];
            if ((t & 3) == 0) {
                int hd = tc >> 2;
                als[node * 4 + hd] = ps;
                ald[node * 4 + hd] = pd;
            }
        }
    }
    psmax = fmaxf(psmax, __shfl_xor(psmax, 16, 64));
    psmax = fmaxf(psmax, __shfl_xor(psmax, 32, 64));
    if ((t & 51) == 0) atomicMax(&lmax[(t >> 2) & 3], enc_f(psmax));
    __syncthreads();
    if (t < 4) atomicMax(gmax + t, lmax[t]);
}

// ---- legacy small GEMM (layer 3: HC=16, H=1) + fused logits + global als-max ----
template<int F, int HC, int H>
__global__ __launch_bounds__(256) void gemm_al_kernel(const float* __restrict__ in,
                                                      const float* __restrict__ W,
                                                      const float* __restrict__ a_s,
                                                      const float* __restrict__ a_d,
                                                      float* __restrict__ h,
                                                      float* __restrict__ als,
                                                      float* __restrict__ ald,
                                                      unsigned* __restrict__ gmax, int n) {
    constexpr int NPB = 256 / HC;
    __shared__ float wl[F * HC];
    __shared__ float xl[NPB * F];
    __shared__ unsigned lmax1;
    const int t = threadIdx.x;
    if (t == 0) lmax1 = 0u;
    for (int i = t; i < F * HC; i += 256) wl[i] = W[i];
    const int node0 = blockIdx.x * NPB;
    for (int i = t; i < NPB * F; i += 256) {
        int node = node0 + i / F;
        xl[i] = (node < n) ? in[node * F + (i % F)] : 0.f;
    }
    __syncthreads();
    const int nl = t / HC, col = t % HC;
    const int node = node0 + nl;
    float acc = 0.f;
#pragma unroll
    for (int k = 0; k < F; ++k) acc += xl[nl * F + k] * wl[k * HC + col];
    float ps = acc * a_s[col];
    float pd = acc * a_d[col];
#pragma unroll
    for (int msk = 1; msk < 16; msk <<= 1) {
        ps += __shfl_xor(ps, msk, 64);
        pd += __shfl_xor(pd, msk, 64);
    }
    if (node < n) {
        h[node * HC + col] = acc;
        if ((col & 15) == 0) {
            int head = col >> 4;
            als[node * H + head] = ps;
            ald[node * H + head] = pd;
        }
    }
    if (H == 1) {
        float psm = (node < n) ? ps : -1e30f;
        psm = fmaxf(psm, __shfl_xor(psm, 16, 64));
        psm = fmaxf(psm, __shfl_xor(psm, 32, 64));
        if ((t & 63) == 0) atomicMax(&lmax1, enc_f(psm));
        __syncthreads();
        if (t == 0) atomicMax(gmax, lmax1);
    }
}

// ---- CSR build phase B: per-slice local counting sort, LDS-staged.
//      Each block computes its own global base (inline prefix over scur). ----
__global__ __launch_bounds__(256) void buildcsr_kernel(const int2* __restrict__ pairs,
                                                       const int* __restrict__ scur,
                                                       int* __restrict__ csr,
                                                       int* __restrict__ off,
                                                       int n, int et, int nsl) {
    __shared__ int hist[SLW], hoff[SLW], hcur[SLW];
    __shared__ int lcsr[CAPS];
    __shared__ int hs[SLW];
    __shared__ int red[256];
    const int sl = blockIdx.x;
    const int lo = sl << SLSH;
    const int t = threadIdx.x;
    int partial = 0;
    for (int i = t; i < sl; i += 256) partial += scur[i];
    red[t] = partial;
    __syncthreads();
    for (int o = 128; o > 0; o >>= 1) {
        if (t < o) red[t] += red[t + o];
        __syncthreads();
    }
    const int gbase = red[0];
    const int cnt = min(scur[sl], CAPS);
    const int2* pp = pairs + (size_t)sl * CAPS;
    if (t < SLW) { hist[t] = 0; hcur[t] = 0; }
    __syncthreads();
    for (int i = t; i < cnt; i += 256) atomicAdd(&hist[pp[i].y - lo], 1);
    __syncthreads();
    if (t < SLW) hs[t] = hist[t];
    __syncthreads();
    for (int o = 1; o < SLW; o <<= 1) {
        int val = (t < SLW && t >= o) ? hs[t - o] : 0;
        __syncthreads();
        if (t < SLW) hs[t] += val;
        __syncthreads();
    }
    if (t < SLW) hoff[t] = hs[t] - hist[t];
    __syncthreads();
    if (t < SLW && lo + t < n) off[lo + t] = gbase + hoff[t];
    if (sl == nsl - 1 && t == 0) off[n] = et;
    for (int i = t; i < cnt; i += 256) {
        int2 p = pp[i];
        int dl = p.y - lo;
        int r = atomicAdd(&hcur[dl], 1);
        lcsr[hoff[dl] + r] = p.x;
    }
    __syncthreads();
    for (int i = t; i < cnt; i += 256) csr[gbase + i] = lcsr[i];
}

// ---- aggregation, H=4 C=16: single-pass (global-bound softmax shift) ----
__global__ __launch_bounds__(256) void agg64_kernel(const int* __restrict__ off,
                                                    const int* __restrict__ csr,
                                                    const float* __restrict__ als,
                                                    const float* __restrict__ ald,
                                                    const float* __restrict__ h,
                                                    const unsigned* __restrict__ gmax,
                                                    const float* __restrict__ bias,
                                                    const float* __restrict__ g,
                                                    const float* __restrict__ bb,
                                                    const float* __restrict__ mm,
                                                    const float* __restrict__ vv,
                                                    float* __restrict__ feat, int n) {
    int wave = (blockIdx.x * blockDim.x + threadIdx.x) >> 6;
    int lane = threadIdx.x & 63;
    if (wave >= n) return;
    const int start = off[wave], end = off[wave + 1], deg = end - start;

    const int ha = lane & 3;
    const int el = lane >> 2;
    const float alda = ald[(wave << 2) + ha];
    const float mh = lrelu(dec_f(gmax[ha]) + alda);  // upper bound (lrelu monotone)

    const int c4 = lane & 15;
    const int hd = c4 >> 2;
    const int eg = lane >> 4;
    float4 acc = {0.f, 0.f, 0.f, 0.f};
    float lsum = 0.f;
    for (int i = 0; i < deg; i += 16) {
        int slot = i + el;
        int s = csr[start + min(slot, deg - 1)];
        float w = __expf(lrelu(als[(s << 2) + ha] + alda) - mh);
        w = (slot < deg) ? w : 0.f;
        lsum += w;
#pragma unroll
        for (int j0 = 0; j0 < 16; j0 += 4) {
            int srcl = ((j0 + eg) << 2) + hd;
            float wj = __shfl(w, srcl, 64);
            int sj = __shfl(s, srcl, 64);
            const float4 hv = *(const float4*)(h + (sj << 6) + (c4 << 2));
            acc.x = fmaf(wj, hv.x, acc.x);
            acc.y = fmaf(wj, hv.y, acc.y);
            acc.z = fmaf(wj, hv.z, acc.z);
            acc.w = fmaf(wj, hv.w, acc.w);
        }
    }
#pragma unroll
    for (int msk = 4; msk < 64; msk <<= 1) lsum += __shfl_xor(lsum, msk, 64);
    float denom = __shfl(lsum, hd, 64);
#pragma unroll
    for (int msk = 16; msk < 64; msk <<= 1) {
        acc.x += __shfl_xor(acc.x, msk, 64);
        acc.y += __shfl_xor(acc.y, msk, 64);
        acc.z += __shfl_xor(acc.z, msk, 64);
        acc.w += __shfl_xor(acc.w, msk, 64);
    }
    if (lane < 16) {
        const int cb = c4 << 2;
        float inv = 1.f / (denom + 1e-16f);
        float4 bi = *(const float4*)(bias + cb);
        float4 gg = *(const float4*)(g + cb);
        float4 bbv = *(const float4*)(bb + cb);
        float4 mmv = *(const float4*)(mm + cb);
        float4 vvv = *(const float4*)(vv + cb);
        float4 o;
        o.x = fmaxf((acc.x * inv + bi.x - mmv.x) * rsqrtf(vvv.x + 1e-5f) * gg.x + bbv.x, 0.f);
        o.y = fmaxf((acc.y * inv + bi.y - mmv.y) * rsqrtf(vvv.y + 1e-5f) * gg.y + bbv.y, 0.f);
        o.z = fmaxf((acc.z * inv + bi.z - mmv.z) * rsqrtf(vvv.z + 1e-5f) * gg.z + bbv.z, 0.f);
        o.w = fmaxf((acc.w * inv + bi.w - mmv.w) * rsqrtf(vvv.w + 1e-5f) * gg.w + bbv.w, 0.f);
        *(float4*)(feat + ((size_t)wave << 6) + cb) = o;
    }
}

// ---- aggregation, H=1 C=16, FUSED with BN/ReLU and the 16->8->1 MLP head ----
__global__ __launch_bounds__(256) void agg16_mlp_kernel(const int* __restrict__ off,
                                                        const int* __restrict__ csr,
                                                        const float* __restrict__ als,
                                                        const float* __restrict__ ald,
                                                        const float* __restrict__ h,
                                                        const unsigned* __restrict__ gmax,
                                                        const float* __restrict__ bias,
                                                        const float* __restrict__ g,
                                                        const float* __restrict__ bb,
                                                        const float* __restrict__ mm,
                                                        const float* __restrict__ vv,
                                                        const float* __restrict__ w1,
                                                        const float* __restrict__ b1,
                                                        const float* __restrict__ w2,
                                                        const float* __restrict__ b2,
                                                        float* __restrict__ out, int n) {
    int wave = (blockIdx.x * blockDim.x + threadIdx.x) >> 6;
    int lane = threadIdx.x & 63;
    if (wave >= n) return;
    const int start = off[wave], end = off[wave + 1], deg = end - start;
    const float aldv = ald[wave];
    const float m = lrelu(dec_f(gmax[0]) + aldv);

    const int eg = lane >> 4, c = lane & 15;
    float acc = 0.f, lsum = 0.f;
    for (int i = 0; i < deg; i += 64) {
        int slot = i + lane;
        int s = csr[start + min(slot, deg - 1)];
        float w = __expf(lrelu(als[s] + aldv) - m);
        w = (slot < deg) ? w : 0.f;
        lsum += w;
#pragma unroll
        for (int j0 = 0; j0 < 64; j0 += 4) {
            int j = j0 + eg;
            float wj = __shfl(w, j, 64);
            int sj = __shfl(s, j, 64);
            acc = fmaf(wj, h[(sj << 4) + c], acc);
        }
    }
#pragma unroll
    for (int msk = 1; msk < 64; msk <<= 1) lsum += __shfl_xor(lsum, msk, 64);
#pragma unroll
    for (int msk = 16; msk < 64; msk <<= 1) acc += __shfl_xor(acc, msk, 64);

    float val = acc / (lsum + 1e-16f) + bias[c];
    val = (val - mm[c]) * rsqrtf(vv[c] + 1e-5f) * g[c] + bb[c];
    val = fmaxf(val, 0.f);

    const int j0 = eg * 2, j1 = j0 + 1;
    float p0 = val * w1[c * 8 + j0];
    float p1 = val * w1[c * 8 + j1];
#pragma unroll
    for (int msk = 1; msk < 16; msk <<= 1) {
        p0 += __shfl_xor(p0, msk, 64);
        p1 += __shfl_xor(p1, msk, 64);
    }
    float hv0 = fmaxf(p0 + b1[j0], 0.f);
    float hv1 = fmaxf(p1 + b1[j1], 0.f);
    float o = hv0 * w2[j0] + hv1 * w2[j1];
#pragma unroll
    for (int msk = 16; msk < 64; msk <<= 1) o += __shfl_xor(o, msk, 64);
    if (lane == 0) out[wave] = o + b2[0];
}

extern "C" void kernel_launch(void* const* d_in, const int* in_sizes, int n_in,
                              void* d_out, int out_size, void* d_ws, size_t ws_size,
                              hipStream_t stream) {
    const float* x    = (const float*)d_in[0];
    const int*   ei   = (const int*)d_in[1];
    const float* W1   = (const float*)d_in[2];
    const float* As1  = (const float*)d_in[3];
    const float* Ad1  = (const float*)d_in[4];
    const float* b1   = (const float*)d_in[5];
    const float* bn1g = (const float*)d_in[6];
    const float* bn1b = (const float*)d_in[7];
    const float* bn1m = (const float*)d_in[8];
    const float* bn1v = (const float*)d_in[9];
    const float* W2   = (const float*)d_in[10];
    const float* As2  = (const float*)d_in[11];
    const float* Ad2  = (const float*)d_in[12];
    const float* b2   = (const float*)d_in[13];
    const float* bn2g = (const float*)d_in[14];
    const float* bn2b = (const float*)d_in[15];
    const float* bn2m = (const float*)d_in[16];
    const float* bn2v = (const float*)d_in[17];
    const float* W3   = (const float*)d_in[18];
    const float* As3  = (const float*)d_in[19];
    const float* Ad3  = (const float*)d_in[20];
    const float* b3   = (const float*)d_in[21];
    const float* bn3g = (const float*)d_in[22];
    const float* bn3b = (const float*)d_in[23];
    const float* bn3m = (const float*)d_in[24];
    const float* bn3v = (const float*)d_in[25];
    const float* fc1w = (const float*)d_in[26];
    const float* fc1b = (const float*)d_in[27];
    const float* fc2w = (const float*)d_in[28];
    const float* fc2b = (const float*)d_in[29];

    const int n  = in_sizes[0] / IN_DIM;  // 50000
    const int ne = in_sizes[1] / 2;       // 1600000
    const int et = ne + n;
    const int nsl = (n + SLW - 1) >> SLSH;  // 391
    const int pblocks = (et + EPA - 1) / EPA;  // 403

    float* h    = (float*)d_ws;
    float* feat = h + (size_t)n * 64;
    float* als  = feat + (size_t)n * 64;
    float* ald  = als + (size_t)n * 4;
    int2* pairs = (int2*)(ald + (size_t)n * 4);
    unsigned* gmax = (unsigned*)(pairs + (size_t)nsl * CAPS);  // gmax1[4] gmax2[4] gmax3[4]
    int* scur   = (int*)(gmax + 12);
    int* off    = scur + nsl;
    int* csr    = off + (n + 1);

    auto cdiv = [](long a, long b) { return (int)((a + b - 1) / b); };

    // ---- memset (gmax + scur) -> [partition || gemm64-L1] -> buildcsr ----
    hipMemsetAsync(gmax, 0, (12 + (size_t)nsl) * sizeof(int), stream);
    part_gemm1_kernel<<<pblocks + cdiv(n, 64), 256, 0, stream>>>(
        ei, scur, pairs, ne, n, nsl, pblocks,
        x, W1, As1, Ad1, h, als, ald, gmax);
    buildcsr_kernel<<<nsl, 256, 0, stream>>>(pairs, scur, csr, off, n, et, nsl);

    // ---- Layer 1 aggregation ----
    agg64_kernel<<<cdiv(n, 4), 256, 0, stream>>>(off, csr, als, ald, h, gmax,
        b1, bn1g, bn1b, bn1m, bn1v, feat, n);

    // ---- Layer 2 ----
    gemm64_al_kernel<64><<<cdiv(n, 64), 256, 0, stream>>>(feat, W2, As2, Ad2, h, als, ald, gmax + 4, n);
    agg64_kernel<<<cdiv(n, 4), 256, 0, stream>>>(off, csr, als, ald, h, gmax + 4,
        b2, bn2g, bn2b, bn2m, bn2v, feat, n);

    // ---- Layer 3 (agg + BN + MLP fused, writes d_out) ----
    gemm_al_kernel<64, 16, 1><<<cdiv(n, 16), 256, 0, stream>>>(feat, W3, As3, Ad3, h, als, ald, gmax + 8, n);
    agg16_mlp_kernel<<<cdiv(n, 4), 256, 0, stream>>>(off, csr, als, ald, h, gmax + 8,
        b3, bn3g, bn3b, bn3m, bn3v, fc1w, fc1b, fc2w, fc2b, (float*)d_out, n);
}

// Round 15
// 385.918 us; speedup vs baseline: 1.0604x; 1.0164x over previous
//
#include <hip/hip_runtime.h>

#define IN_DIM 128
#define SLW 128        // dst-slice width for the bucket sort (power of 2)
#define SLSH 7         // log2(SLW)
#define CAPS 6144      // per-slice pair capacity
#define EPA 4096       // edges per phase-A block
#define MAXSL 512      // static LDS sizing for phase A (>= nsl)

__device__ __forceinline__ float lrelu(float x) { return x > 0.f ? x : 0.2f * x; }

// order-preserving float->uint for atomicMax (0x00000000 == -inf sentinel)
__device__ __forceinline__ unsigned enc_f(float x) {
    unsigned b = __float_as_uint(x);
    return (b & 0x80000000u) ? ~b : (b | 0x80000000u);
}
__device__ __forceinline__ float dec_f(unsigned e) {
    unsigned b = (e & 0x80000000u) ? (e & 0x7fffffffu) : ~e;
    return __uint_as_float(b);
}

// ---- MERGED: edge partition (blocks [0, pblocks)) + L1 GEMM (rest).
//      LDS overlaid union, K staged in 64-wide chunks -> ~34 KB, 4 blocks/CU. ----
__global__ __launch_bounds__(256) void part_gemm1_kernel(const int* __restrict__ ei,
                                                         int* __restrict__ scur,
                                                         int2* __restrict__ pairs,
                                                         int ne, int n, int nsl, int pblocks,
                                                         const float* __restrict__ in,
                                                         const float* __restrict__ W,
                                                         const float* __restrict__ a_s,
                                                         const float* __restrict__ a_d,
                                                         float* __restrict__ h,
                                                         float* __restrict__ als,
                                                         float* __restrict__ ald,
                                                         unsigned* __restrict__ gmax) {
    constexpr int F = 128;
    // union: gemm {wl[64*64] | xl[64*68]} vs partition {lcnt|lbase|lcur}[MAXSL]
    __shared__ float smem[64 * 64 + 64 * 68];   // 33792 B
    __shared__ unsigned lmax[4];
    const int t = threadIdx.x;

    if (blockIdx.x < pblocks) {
        // ---------------- partition path (overlaid LDS) ----------------
        int* lcnt  = (int*)smem;
        int* lbase = lcnt + MAXSL;
        int* lcur  = lbase + MAXSL;
        for (int i = t; i < MAXSL; i += 256) lcnt[i] = 0;
        __syncthreads();
        const int base = blockIdx.x * EPA;
        const int end = min(ne + n, base + EPA);
        for (int e = base + t; e < end; e += 256) {
            int d = (e < ne) ? ei[ne + e] : (e - ne);
            atomicAdd(&lcnt[d >> SLSH], 1);
        }
        __syncthreads();
        for (int s = t; s < nsl; s += 256) {
            lbase[s] = lcnt[s] ? atomicAdd(scur + s, lcnt[s]) : 0;
            lcur[s] = 0;
        }
        __syncthreads();
        for (int e = base + t; e < end; e += 256) {
            int s, d;
            if (e < ne) { s = ei[e]; d = ei[ne + e]; } else { s = d = e - ne; }
            int sl = d >> SLSH;
            int pos = lbase[sl] + atomicAdd(&lcur[sl], 1);
            if (pos < CAPS) pairs[(size_t)sl * CAPS + pos] = make_int2(s, d);
        }
        return;
    }

    // ---------------- gemm64 path (layer 1, F=128, K staged 64-wide) ----------------
    float* wl = smem;               // [klocal][col], 64*64
    float* xl = smem + 64 * 64;     // [node][klocal], stride 68
    const int node0 = (blockIdx.x - pblocks) * 64;
    if (t < 4) lmax[t] = 0u;
    const int tn = t >> 4;
    const int tc = t & 15;
    float4 acc[4] = {{0,0,0,0},{0,0,0,0},{0,0,0,0},{0,0,0,0}};

    for (int ks = 0; ks < F; ks += 64) {
        if (ks) __syncthreads();   // drain previous stage's reads
        for (int idx = t * 4; idx < 64 * 64; idx += 1024)
            *(float4*)&wl[idx] = *(const float4*)(W + ks * 64 + idx);
        for (int idx = t * 4; idx < 64 * 64; idx += 1024) {
            int node = idx >> 6, kk = idx & 63;
            float4 v = make_float4(0.f, 0.f, 0.f, 0.f);
            if (node0 + node < n) v = *(const float4*)(in + (size_t)(node0 + node) * F + ks + kk);
            *(float4*)&xl[node * 68 + kk] = v;
        }
        __syncthreads();
        for (int k0 = 0; k0 < 64; k0 += 4) {
            float4 xa[4];
#pragma unroll
            for (int i = 0; i < 4; ++i) xa[i] = *(const float4*)&xl[(tn * 4 + i) * 68 + k0];
#pragma unroll
            for (int kk = 0; kk < 4; ++kk) {
                float4 wv = *(const float4*)&wl[(k0 + kk) * 64 + tc * 4];
#pragma unroll
                for (int i = 0; i < 4; ++i) {
                    float xv = (kk == 0) ? xa[i].x : (kk == 1) ? xa[i].y : (kk == 2) ? xa[i].z : xa[i].w;
                    acc[i].x = fmaf(xv, wv.x, acc[i].x);
                    acc[i].y = fmaf(xv, wv.y, acc[i].y);
                    acc[i].z = fmaf(xv, wv.z, acc[i].z);
                    acc[i].w = fmaf(xv, wv.w, acc[i].w);
                }
            }
        }
    }

    const float4 asv = *(const float4*)(a_s + tc * 4);
    const float4 adv = *(const float4*)(a_d + tc * 4);
    float psmax = -1e30f;
#pragma unroll
    for (int i = 0; i < 4; ++i) {
        int node = node0 + tn * 4 + i;
        float ps = acc[i].x * asv.x + acc[i].y * asv.y + acc[i].z * asv.z + acc[i].w * asv.w;
        float pd = acc[i].x * adv.x + acc[i].y * adv.y + acc[i].z * adv.z + acc[i].w * adv.w;
        ps += __shfl_xor(ps, 1, 64); ps += __shfl_xor(ps, 2, 64);
        pd += __shfl_xor(pd, 1, 64); pd += __shfl_xor(pd, 2, 64);
        if (node < n) {
            psmax = fmaxf(psmax, ps);
            *(float4*)(h + (size_t)node * 64 + tc * 4) = acc[i];
            if ((t & 3) == 0) {
                int hd = tc >> 2;
                als[node * 4 + hd] = ps;
                ald[node * 4 + hd] = pd;
            }
        }
    }
    psmax = fmaxf(psmax, __shfl_xor(psmax, 16, 64));
    psmax = fmaxf(psmax, __shfl_xor(psmax, 32, 64));
    if ((t & 51) == 0) atomicMax(&lmax[(t >> 2) & 3], enc_f(psmax));
    __syncthreads();
    if (t < 4) atomicMax(gmax + t, lmax[t]);
}

// ---- register-blocked node GEMM (HC=64, H=4), standalone (layer 2, F=64) ----
template<int F>
__global__ __launch_bounds__(256) void gemm64_al_kernel(const float* __restrict__ in,
                                                        const float* __restrict__ W,
                                                        const float* __restrict__ a_s,
                                                        const float* __restrict__ a_d,
                                                        float* __restrict__ h,
                                                        float* __restrict__ als,
                                                        float* __restrict__ ald,
                                                        unsigned* __restrict__ gmax, int n) {
    constexpr int XS = F + 4;
    __shared__ float wl[F * 64];
    __shared__ float xl[64 * XS];
    __shared__ unsigned lmax[4];
    const int t = threadIdx.x;
    const int node0 = blockIdx.x * 64;
    if (t < 4) lmax[t] = 0u;
    for (int idx = t * 4; idx < F * 64; idx += 1024)
        *(float4*)&wl[idx] = *(const float4*)(W + idx);
    for (int idx = t * 4; idx < 64 * F; idx += 1024) {
        int node = idx / F, k = idx - node * F;
        float4 v = make_float4(0.f, 0.f, 0.f, 0.f);
        if (node0 + node < n) v = *(const float4*)(in + (size_t)(node0 + node) * F + k);
        *(float4*)&xl[node * XS + k] = v;
    }
    __syncthreads();

    const int tn = t >> 4;
    const int tc = t & 15;
    float4 acc[4] = {{0,0,0,0},{0,0,0,0},{0,0,0,0},{0,0,0,0}};
    for (int k0 = 0; k0 < F; k0 += 4) {
        float4 xa[4];
#pragma unroll
        for (int i = 0; i < 4; ++i) xa[i] = *(const float4*)&xl[(tn * 4 + i) * XS + k0];
#pragma unroll
        for (int kk = 0; kk < 4; ++kk) {
            float4 wv = *(const float4*)&wl[(k0 + kk) * 64 + tc * 4];
#pragma unroll
            for (int i = 0; i < 4; ++i) {
                float xv = (kk == 0) ? xa[i].x : (kk == 1) ? xa[i].y : (kk == 2) ? xa[i].z : xa[i].w;
                acc[i].x = fmaf(xv, wv.x, acc[i].x);
                acc[i].y = fmaf(xv, wv.y, acc[i].y);
                acc[i].z = fmaf(xv, wv.z, acc[i].z);
                acc[i].w = fmaf(xv, wv.w, acc[i].w);
            }
        }
    }
    const float4 asv = *(const float4*)(a_s + tc * 4);
    const float4 adv = *(const float4*)(a_d + tc * 4);
    float psmax = -1e30f;
#pragma unroll
    for (int i = 0; i < 4; ++i) {
        int node = node0 + tn * 4 + i;
        float ps = acc[i].x * asv.x + acc[i].y * asv.y + acc[i].z * asv.z + acc[i].w * asv.w;
        float pd = acc[i].x * adv.x + acc[i].y * adv.y + acc[i].z * adv.z + acc[i].w * adv.w;
        ps += __shfl_xor(ps, 1, 64); ps += __shfl_xor(ps, 2, 64);
        pd += __shfl_xor(pd, 1, 64); pd += __shfl_xor(pd, 2, 64);
        if (node < n) {
            psmax = fmaxf(psmax, ps);
            *(float4*)(h + (size_t)node * 64 + tc * 4) = acc[i];
            if ((t & 3) == 0) {
                int hd = tc >> 2;
                als[node * 4 + hd] = ps;
                ald[node * 4 + hd] = pd;
            }
        }
    }
    psmax = fmaxf(psmax, __shfl_xor(psmax, 16, 64));
    psmax = fmaxf(psmax, __shfl_xor(psmax, 32, 64));
    if ((t & 51) == 0) atomicMax(&lmax[(t >> 2) & 3], enc_f(psmax));
    __syncthreads();
    if (t < 4) atomicMax(gmax + t, lmax[t]);
}

// ---- legacy small GEMM (layer 3: HC=16, H=1) + fused logits + global als-max ----
template<int F, int HC, int H>
__global__ __launch_bounds__(256) void gemm_al_kernel(const float* __restrict__ in,
                                                      const float* __restrict__ W,
                                                      const float* __restrict__ a_s,
                                                      const float* __restrict__ a_d,
                                                      float* __restrict__ h,
                                                      float* __restrict__ als,
                                                      float* __restrict__ ald,
                                                      unsigned* __restrict__ gmax, int n) {
    constexpr int NPB = 256 / HC;
    __shared__ float wl[F * HC];
    __shared__ float xl[NPB * F];
    __shared__ unsigned lmax1;
    const int t = threadIdx.x;
    if (t == 0) lmax1 = 0u;
    for (int i = t; i < F * HC; i += 256) wl[i] = W[i];
    const int node0 = blockIdx.x * NPB;
    for (int i = t; i < NPB * F; i += 256) {
        int node = node0 + i / F;
        xl[i] = (node < n) ? in[node * F + (i % F)] : 0.f;
    }
    __syncthreads();
    const int nl = t / HC, col = t % HC;
    const int node = node0 + nl;
    float acc = 0.f;
#pragma unroll
    for (int k = 0; k < F; ++k) acc += xl[nl * F + k] * wl[k * HC + col];
    float ps = acc * a_s[col];
    float pd = acc * a_d[col];
#pragma unroll
    for (int msk = 1; msk < 16; msk <<= 1) {
        ps += __shfl_xor(ps, msk, 64);
        pd += __shfl_xor(pd, msk, 64);
    }
    if (node < n) {
        h[node * HC + col] = acc;
        if ((col & 15) == 0) {
            int head = col >> 4;
            als[node * H + head] = ps;
            ald[node * H + head] = pd;
        }
    }
    if (H == 1) {
        float psm = (node < n) ? ps : -1e30f;
        psm = fmaxf(psm, __shfl_xor(psm, 16, 64));
        psm = fmaxf(psm, __shfl_xor(psm, 32, 64));
        if ((t & 63) == 0) atomicMax(&lmax1, enc_f(psm));
        __syncthreads();
        if (t == 0) atomicMax(gmax, lmax1);
    }
}

// ---- CSR build phase B: per-slice local counting sort, LDS-staged ----
__global__ __launch_bounds__(256) void buildcsr_kernel(const int2* __restrict__ pairs,
                                                       const int* __restrict__ scur,
                                                       int* __restrict__ csr,
                                                       int* __restrict__ off,
                                                       int n, int et, int nsl) {
    __shared__ int hist[SLW], hoff[SLW], hcur[SLW];
    __shared__ int lcsr[CAPS];
    __shared__ int hs[SLW];
    __shared__ int red[256];
    const int sl = blockIdx.x;
    const int lo = sl << SLSH;
    const int t = threadIdx.x;
    int partial = 0;
    for (int i = t; i < sl; i += 256) partial += scur[i];
    red[t] = partial;
    __syncthreads();
    for (int o = 128; o > 0; o >>= 1) {
        if (t < o) red[t] += red[t + o];
        __syncthreads();
    }
    const int gbase = red[0];
    const int cnt = min(scur[sl], CAPS);
    const int2* pp = pairs + (size_t)sl * CAPS;
    if (t < SLW) { hist[t] = 0; hcur[t] = 0; }
    __syncthreads();
    for (int i = t; i < cnt; i += 256) atomicAdd(&hist[pp[i].y - lo], 1);
    __syncthreads();
    if (t < SLW) hs[t] = hist[t];
    __syncthreads();
    for (int o = 1; o < SLW; o <<= 1) {
        int val = (t < SLW && t >= o) ? hs[t - o] : 0;
        __syncthreads();
        if (t < SLW) hs[t] += val;
        __syncthreads();
    }
    if (t < SLW) hoff[t] = hs[t] - hist[t];
    __syncthreads();
    if (t < SLW && lo + t < n) off[lo + t] = gbase + hoff[t];
    if (sl == nsl - 1 && t == 0) off[n] = et;
    for (int i = t; i < cnt; i += 256) {
        int2 p = pp[i];
        int dl = p.y - lo;
        int r = atomicAdd(&hcur[dl], 1);
        lcsr[hoff[dl] + r] = p.x;
    }
    __syncthreads();
    for (int i = t; i < cnt; i += 256) csr[gbase + i] = lcsr[i];
}

// ---- aggregation, H=4 C=16: single-pass (global-bound softmax shift) ----
__global__ __launch_bounds__(256) void agg64_kernel(const int* __restrict__ off,
                                                    const int* __restrict__ csr,
                                                    const float* __restrict__ als,
                                                    const float* __restrict__ ald,
                                                    const float* __restrict__ h,
                                                    const unsigned* __restrict__ gmax,
                                                    const float* __restrict__ bias,
                                                    const float* __restrict__ g,
                                                    const float* __restrict__ bb,
                                                    const float* __restrict__ mm,
                                                    const float* __restrict__ vv,
                                                    float* __restrict__ feat, int n) {
    int wave = (blockIdx.x * blockDim.x + threadIdx.x) >> 6;
    int lane = threadIdx.x & 63;
    if (wave >= n) return;
    const int start = off[wave], end = off[wave + 1], deg = end - start;

    const int ha = lane & 3;
    const int el = lane >> 2;
    const float alda = ald[(wave << 2) + ha];
    const float mh = lrelu(dec_f(gmax[ha]) + alda);  // upper bound (lrelu monotone)

    const int c4 = lane & 15;
    const int hd = c4 >> 2;
    const int eg = lane >> 4;
    float4 acc = {0.f, 0.f, 0.f, 0.f};
    float lsum = 0.f;
    for (int i = 0; i < deg; i += 16) {
        int slot = i + el;
        int s = csr[start + min(slot, deg - 1)];
        float w = __expf(lrelu(als[(s << 2) + ha] + alda) - mh);
        w = (slot < deg) ? w : 0.f;
        lsum += w;
#pragma unroll
        for (int j0 = 0; j0 < 16; j0 += 4) {
            int srcl = ((j0 + eg) << 2) + hd;
            float wj = __shfl(w, srcl, 64);
            int sj = __shfl(s, srcl, 64);
            const float4 hv = *(const float4*)(h + (sj << 6) + (c4 << 2));
            acc.x = fmaf(wj, hv.x, acc.x);
            acc.y = fmaf(wj, hv.y, acc.y);
            acc.z = fmaf(wj, hv.z, acc.z);
            acc.w = fmaf(wj, hv.w, acc.w);
        }
    }
#pragma unroll
    for (int msk = 4; msk < 64; msk <<= 1) lsum += __shfl_xor(lsum, msk, 64);
    float denom = __shfl(lsum, hd, 64);
#pragma unroll
    for (int msk = 16; msk < 64; msk <<= 1) {
        acc.x += __shfl_xor(acc.x, msk, 64);
        acc.y += __shfl_xor(acc.y, msk, 64);
        acc.z += __shfl_xor(acc.z, msk, 64);
        acc.w += __shfl_xor(acc.w, msk, 64);
    }
    if (lane < 16) {
        const int cb = c4 << 2;
        float inv = 1.f / (denom + 1e-16f);
        float4 bi = *(const float4*)(bias + cb);
        float4 gg = *(const float4*)(g + cb);
        float4 bbv = *(const float4*)(bb + cb);
        float4 mmv = *(const float4*)(mm + cb);
        float4 vvv = *(const float4*)(vv + cb);
        float4 o;
        o.x = fmaxf((acc.x * inv + bi.x - mmv.x) * rsqrtf(vvv.x + 1e-5f) * gg.x + bbv.x, 0.f);
        o.y = fmaxf((acc.y * inv + bi.y - mmv.y) * rsqrtf(vvv.y + 1e-5f) * gg.y + bbv.y, 0.f);
        o.z = fmaxf((acc.z * inv + bi.z - mmv.z) * rsqrtf(vvv.z + 1e-5f) * gg.z + bbv.z, 0.f);
        o.w = fmaxf((acc.w * inv + bi.w - mmv.w) * rsqrtf(vvv.w + 1e-5f) * gg.w + bbv.w, 0.f);
        *(float4*)(feat + ((size_t)wave << 6) + cb) = o;
    }
}

// ---- aggregation, H=1 C=16, FUSED with BN/ReLU and the 16->8->1 MLP head ----
__global__ __launch_bounds__(256) void agg16_mlp_kernel(const int* __restrict__ off,
                                                        const int* __restrict__ csr,
                                                        const float* __restrict__ als,
                                                        const float* __restrict__ ald,
                                                        const float* __restrict__ h,
                                                        const unsigned* __restrict__ gmax,
                                                        const float* __restrict__ bias,
                                                        const float* __restrict__ g,
                                                        const float* __restrict__ bb,
                                                        const float* __restrict__ mm,
                                                        const float* __restrict__ vv,
                                                        const float* __restrict__ w1,
                                                        const float* __restrict__ b1,
                                                        const float* __restrict__ w2,
                                                        const float* __restrict__ b2,
                                                        float* __restrict__ out, int n) {
    int wave = (blockIdx.x * blockDim.x + threadIdx.x) >> 6;
    int lane = threadIdx.x & 63;
    if (wave >= n) return;
    const int start = off[wave], end = off[wave + 1], deg = end - start;
    const float aldv = ald[wave];
    const float m = lrelu(dec_f(gmax[0]) + aldv);

    const int eg = lane >> 4, c = lane & 15;
    float acc = 0.f, lsum = 0.f;
    for (int i = 0; i < deg; i += 64) {
        int slot = i + lane;
        int s = csr[start + min(slot, deg - 1)];
        float w = __expf(lrelu(als[s] + aldv) - m);
        w = (slot < deg) ? w : 0.f;
        lsum += w;
#pragma unroll
        for (int j0 = 0; j0 < 64; j0 += 4) {
            int j = j0 + eg;
            float wj = __shfl(w, j, 64);
            int sj = __shfl(s, j, 64);
            acc = fmaf(wj, h[(sj << 4) + c], acc);
        }
    }
#pragma unroll
    for (int msk = 1; msk < 64; msk <<= 1) lsum += __shfl_xor(lsum, msk, 64);
#pragma unroll
    for (int msk = 16; msk < 64; msk <<= 1) acc += __shfl_xor(acc, msk, 64);

    float val = acc / (lsum + 1e-16f) + bias[c];
    val = (val - mm[c]) * rsqrtf(vv[c] + 1e-5f) * g[c] + bb[c];
    val = fmaxf(val, 0.f);

    const int j0 = eg * 2, j1 = j0 + 1;
    float p0 = val * w1[c * 8 + j0];
    float p1 = val * w1[c * 8 + j1];
#pragma unroll
    for (int msk = 1; msk < 16; msk <<= 1) {
        p0 += __shfl_xor(p0, msk, 64);
        p1 += __shfl_xor(p1, msk, 64);
    }
    float hv0 = fmaxf(p0 + b1[j0], 0.f);
    float hv1 = fmaxf(p1 + b1[j1], 0.f);
    float o = hv0 * w2[j0] + hv1 * w2[j1];
#pragma unroll
    for (int msk = 16; msk < 64; msk <<= 1) o += __shfl_xor(o, msk, 64);
    if (lane == 0) out[wave] = o + b2[0];
}

extern "C" void kernel_launch(void* const* d_in, const int* in_sizes, int n_in,
                              void* d_out, int out_size, void* d_ws, size_t ws_size,
                              hipStream_t stream) {
    const float* x    = (const float*)d_in[0];
    const int*   ei   = (const int*)d_in[1];
    const float* W1   = (const float*)d_in[2];
    const float* As1  = (const float*)d_in[3];
    const float* Ad1  = (const float*)d_in[4];
    const float* b1   = (const float*)d_in[5];
    const float* bn1g = (const float*)d_in[6];
    const float* bn1b = (const float*)d_in[7];
    const float* bn1m = (const float*)d_in[8];
    const float* bn1v = (const float*)d_in[9];
    const float* W2   = (const float*)d_in[10];
    const float* As2  = (const float*)d_in[11];
    const float* Ad2  = (const float*)d_in[12];
    const float* b2   = (const float*)d_in[13];
    const float* bn2g = (const float*)d_in[14];
    const float* bn2b = (const float*)d_in[15];
    const float* bn2m = (const float*)d_in[16];
    const float* bn2v = (const float*)d_in[17];
    const float* W3   = (const float*)d_in[18];
    const float* As3  = (const float*)d_in[19];
    const float* Ad3  = (const float*)d_in[20];
    const float* b3   = (const float*)d_in[21];
    const float* bn3g = (const float*)d_in[22];
    const float* bn3b = (const float*)d_in[23];
    const float* bn3m = (const float*)d_in[24];
    const float* bn3v = (const float*)d_in[25];
    const float* fc1w = (const float*)d_in[26];
    const float* fc1b = (const float*)d_in[27];
    const float* fc2w = (const float*)d_in[28];
    const float* fc2b = (const float*)d_in[29];

    const int n  = in_sizes[0] / IN_DIM;  // 50000
    const int ne = in_sizes[1] / 2;       // 1600000
    const int et = ne + n;
    const int nsl = (n + SLW - 1) >> SLSH;  // 391
    const int pblocks = (et + EPA - 1) / EPA;  // 403

    float* h    = (float*)d_ws;
    float* feat = h + (size_t)n * 64;
    float* als  = feat + (size_t)n * 64;
    float* ald  = als + (size_t)n * 4;
    int2* pairs = (int2*)(ald + (size_t)n * 4);
    unsigned* gmax = (unsigned*)(pairs + (size_t)nsl * CAPS);  // gmax1[4] gmax2[4] gmax3[4]
    int* scur   = (int*)(gmax + 12);
    int* off    = scur + nsl;
    int* csr    = off + (n + 1);

    auto cdiv = [](long a, long b) { return (int)((a + b - 1) / b); };

    // ---- memset (gmax + scur) -> [partition || gemm64-L1] -> buildcsr ----
    hipMemsetAsync(gmax, 0, (12 + (size_t)nsl) * sizeof(int), stream);
    part_gemm1_kernel<<<pblocks + cdiv(n, 64), 256, 0, stream>>>(
        ei, scur, pairs, ne, n, nsl, pblocks,
        x, W1, As1, Ad1, h, als, ald, gmax);
    buildcsr_kernel<<<nsl, 256, 0, stream>>>(pairs, scur, csr, off, n, et, nsl);

    // ---- Layer 1 aggregation ----
    agg64_kernel<<<cdiv(n, 4), 256, 0, stream>>>(off, csr, als, ald, h, gmax,
        b1, bn1g, bn1b, bn1m, bn1v, feat, n);

    // ---- Layer 2 ----
    gemm64_al_kernel<64><<<cdiv(n, 64), 256, 0, stream>>>(feat, W2, As2, Ad2, h, als, ald, gmax + 4, n);
    agg64_kernel<<<cdiv(n, 4), 256, 0, stream>>>(off, csr, als, ald, h, gmax + 4,
        b2, bn2g, bn2b, bn2m, bn2v, feat, n);

    // ---- Layer 3 (agg + BN + MLP fused, writes d_out) ----
    gemm_al_kernel<64, 16, 1><<<cdiv(n, 16), 256, 0, stream>>>(feat, W3, As3, Ad3, h, als, ald, gmax + 8, n);
    agg16_mlp_kernel<<<cdiv(n, 4), 256, 0, stream>>>(off, csr, als, ald, h, gmax + 8,
        b3, bn3g, bn3b, bn3m, bn3v, fc1w, fc1b, fc2w, fc2b, (float*)d_out, n);
}